// Round 7
// baseline (908.202 us; speedup 1.0000x reference)
//
#include <hip/hip_runtime.h>

#define NN 100000      // nodes
#define NE 1000000     // edges
#define NG 1024        // graphs
#define NSG 128        // subgraphs
#define EF 32          // edge feature dim
#define HH 64          // hidden
#define NOUT 32        // output classes
#define NL 3           // layers
#define NWAVE (NE / 64)   // 15625 edge waves, 64 edges (4 groups) each
#define NGRP_N (NN / 16)  // 6250 node groups of 16

typedef __attribute__((ext_vector_type(8))) short bf16x8;
typedef __attribute__((ext_vector_type(4))) float f32x4;

// rotated-EM index: stride 64 with per-row column rotation; bank behavior
// identical to a stride-68 pad (bank = (c + row*4) mod 32) at zero footprint.
#define EMIDX(row, c) ((row) * 64 + (((c) + (row) * 4) & 63))

// wave-uniform broadcast of lane l's value (v_readlane -> SGPR)
__device__ __forceinline__ float bcastf(float v, int l) {
    return __int_as_float(__builtin_amdgcn_readlane(__float_as_int(v), l));
}

// fp32 -> bf16 (RNE)
__device__ __forceinline__ short f2bf(float x) {
    unsigned u = __float_as_uint(x);
    u += 0x7FFFu + ((u >> 16) & 1u);
    return (short)(u >> 16);
}

// bf16 -> fp32 (exact)
__device__ __forceinline__ float bf2f(short h) {
    return __uint_as_float(((unsigned)(unsigned short)h) << 16);
}

// wave-internal LDS producer->consumer handoff (no cross-wave sharing)
__device__ __forceinline__ void wave_lds_sync() {
    __builtin_amdgcn_wave_barrier();
    asm volatile("s_waitcnt lgkmcnt(0)" ::: "memory");
    __builtin_amdgcn_wave_barrier();
}

// async global->LDS, 16B per lane; LDS dest = wave-uniform base + lane*16
__device__ __forceinline__ void gld16(const float* g, float* l) {
    __builtin_amdgcn_global_load_lds(
        (const __attribute__((address_space(1))) void*)g,
        (__attribute__((address_space(3))) void*)l, 16, 0, 0);
}

#define WAITVM_(n) asm volatile("s_waitcnt vmcnt(" #n ")" ::: "memory")
#define WAITVM(n) WAITVM_(n)

// ---------------------------------------------------------------------------
// cnt (graph node counts) + norm (subgraph weight sums) in one launch
__global__ void prep_kernel(const int* __restrict__ batch, const int* __restrict__ sgb,
                            const float* __restrict__ w,
                            float* __restrict__ cnt, float* __restrict__ norm) {
    int i = blockIdx.x * blockDim.x + threadIdx.x;
    if (i < NN) atomicAdd(&cnt[batch[i]], 1.0f);
    if (i < NG) atomicAdd(&norm[sgb[i]], w[i]);
}

// --------------------------- edge counting-sort ----------------------------
__global__ void hist_kernel(const int* __restrict__ eidx, int* __restrict__ off) {
    int e = blockIdx.x * 256 + threadIdx.x;
    if (e < NE) atomicAdd(&off[eidx[NE + e]], 1);
}

__global__ void scan1(int* __restrict__ off, int* __restrict__ bsum) {
    __shared__ int s[256];
    const int i = blockIdx.x * 256 + threadIdx.x;
    const int v = (i < NN) ? off[i] : 0;
    s[threadIdx.x] = v; __syncthreads();
    for (int d = 1; d < 256; d <<= 1) {
        const int t = (threadIdx.x >= d) ? s[threadIdx.x - d] : 0;
        __syncthreads(); s[threadIdx.x] += t; __syncthreads();
    }
    if (i < NN) off[i] = s[threadIdx.x] - v;          // exclusive
    if (threadIdx.x == 255) bsum[blockIdx.x] = s[255];
}

__global__ void scan2(int* __restrict__ bsum, int nb) {
    __shared__ int s[512];
    const int v = (threadIdx.x < nb) ? bsum[threadIdx.x] : 0;
    s[threadIdx.x] = v; __syncthreads();
    for (int d = 1; d < 512; d <<= 1) {
        const int t = (threadIdx.x >= d) ? s[threadIdx.x - d] : 0;
        __syncthreads(); s[threadIdx.x] += t; __syncthreads();
    }
    if (threadIdx.x < nb) bsum[threadIdx.x] = s[threadIdx.x] - v;  // exclusive
}

__global__ void scan3(int* __restrict__ off, const int* __restrict__ bsum) {
    const int i = blockIdx.x * 256 + threadIdx.x;
    if (i < NN) off[i] += bsum[blockIdx.x];
}

__global__ void scatter_kernel(const int* __restrict__ eidx, int* __restrict__ off,
                               int* __restrict__ perm_s, int* __restrict__ src_s,
                               int* __restrict__ dst_s) {
    int e = blockIdx.x * 256 + threadIdx.x;
    if (e < NE) {
        const int d = eidx[NE + e];
        const int p = atomicAdd(&off[d], 1);
        perm_s[p] = e;
        src_s[p]  = eidx[e];
        dst_s[p]  = d;
    }
}

// ---------------------------------------------------------------------------
// Edge pass via MFMA over dst-SORTED edges.
// v7: the proven v5 depth-1 pipeline + wait ledger, with EM re-expressed as
// rotated stride-64 (EMIDX) instead of padded stride-68. Same bank behavior,
// 1KB/wave less LDS -> exactly 40960B/block -> 4 blocks/CU (16 waves).
//   issue order: [fence] EA0,HG0 | EA1 .. HG1 | EA2 .. HG2 | EA3 .. HG3
//   EA waits: 4,4,4,4   HG waits: 2,2,2,0   (N <= #younger DMA loads, safe)
__global__ __launch_bounds__(256, 4) void edge_mfma(
    const float* __restrict__ hin,       // [NN,64]
    const float* __restrict__ eattr,     // [NE,32]
    const int*   __restrict__ perm_s,    // [NE] sorted->orig edge id
    const int*   __restrict__ src_s,     // [NE] src of sorted edge
    const int*   __restrict__ dst_s,     // [NE] dst of sorted edge (nondecreasing)
    const float* __restrict__ w1,        // [32,64]
    const float* __restrict__ b1,        // [64]
    const float* __restrict__ w2,        // [64,64]
    const float* __restrict__ b2,        // [64]
    float*       __restrict__ agg)       // [NN,64]
{
    __shared__ float ldsall[4][2560];    // per-wave: EM/T | HG | EA = 10240B
    const int lane = threadIdx.x & 63;
    const int wv   = threadIdx.x >> 6;
    const int col  = lane & 15;          // MFMA: B col / C col / A row
    const int quad = lane >> 4;
    float* EM = &ldsall[wv][0];          // fp32 rotated [16][64] (GEMM2 out)
    short* T  = (short*)EM;              // bf16 [16][72] union (GEMM1 out, 576fl)
    float* HG = &ldsall[wv][1024];       // fp32 [16][64] gathered hin rows
    float* EA = &ldsall[wv][2048];       // fp32 [16][32] eattr rows (chunk-swizzled)

    const int wid = __builtin_amdgcn_readfirstlane(
        (blockIdx.x * 256 + (int)threadIdx.x) >> 6);
    if (wid >= NWAVE) return;
    const int ebase = wid * 64;

    // --- weight fragments, built once per wave ---
    bf16x8 B1f[4];
    #pragma unroll
    for (int nt = 0; nt < 4; ++nt)
        #pragma unroll
        for (int j = 0; j < 8; ++j)
            B1f[nt][j] = f2bf(w1[(quad * 8 + j) * HH + nt * 16 + col]);
    bf16x8 B2f[2][4];
    #pragma unroll
    for (int ks = 0; ks < 2; ++ks)
        #pragma unroll
        for (int nt = 0; nt < 4; ++nt)
            #pragma unroll
            for (int j = 0; j < 8; ++j)
                B2f[ks][nt][j] = f2bf(w2[(ks * 32 + quad * 8 + j) * HH + nt * 16 + col]);
    float b1v[4], b2v[4];
    #pragma unroll
    for (int nt = 0; nt < 4; ++nt) {
        b1v[nt] = b1[nt * 16 + col];
        b2v[nt] = b2[nt * 16 + col];
    }

    // --- whole-wave edge indices (one load each, resident all 4 groups) ---
    const int sv_all = src_s[ebase + lane];
    const int dv_all = dst_s[ebase + lane];
    const int pe_all = perm_s[ebase + lane];

    // EA DMA source swizzle: slot s of row r receives global 16B-chunk s^(r&7)
    const int ea_srcchunk = (lane & 7) ^ ((lane >> 3) & 7);
    const int ea_subrow   = lane >> 3;        // row within 8-row DMA block
    const int hg_subrow   = lane >> 4;        // row within 4-row DMA block
    const int hg_off      = (lane & 15) * 4;  // float offset within hin row

    // 2 DMAs staging group g's 16 eattr rows (128B each) into EA
    #define ISSUE_EA(g)                                                        \
        {                                                                      \
            _Pragma("unroll")                                                  \
            for (int b = 0; b < 2; ++b) {                                      \
                const int srow = (g) * 16 + b * 8 + ea_subrow;                 \
                const int pe   = __shfl(pe_all, srow, 64);                     \
                gld16(eattr + (size_t)pe * EF + ea_srcchunk * 4,               \
                      EA + b * 256);                                           \
            }                                                                  \
        }
    // 4 DMAs staging group g's 16 hin gather rows (256B each) into HG
    #define ISSUE_HG(g)                                                        \
        {                                                                      \
            _Pragma("unroll")                                                  \
            for (int b = 0; b < 4; ++b) {                                      \
                const int srow = (g) * 16 + b * 4 + hg_subrow;                 \
                const int s    = __shfl(sv_all, srow, 64);                     \
                gld16(hin + (size_t)s * HH + hg_off, HG + b * 256);            \
            }                                                                  \
        }

    // fence: no compiler-scheduled vmem may sit inside the counted FIFO
    WAITVM(0);
    __builtin_amdgcn_sched_barrier(0);

    // prologue: EA0(2), HG0(4)
    ISSUE_EA(0);
    ISSUE_HG(0);

    int   cur = -1;       // current dst segment (wave-uniform)
    float acc = 0.0f;     // per-lane feature accumulator

    #pragma unroll
    for (int gi = 0; gi < 4; ++gi) {
        // EA[gi] resident: 4 younger DMA loads (HG[gi]) in FIFO
        WAITVM(4);
        __builtin_amdgcn_sched_barrier(0);

        // A1-frag from EA (chunk-swizzled): lane reads row=col, chunks 2q,2q+1
        const int sbase = (2 * quad) ^ (col & 6);
        const float4 fa = *(const float4*)&EA[col * 32 + sbase * 4];
        const float4 fb = *(const float4*)&EA[col * 32 + sbase * 4 + 4];
        const bool odd = (col & 1);
        const float4 lo = odd ? fb : fa;
        const float4 hi = odd ? fa : fb;
        bf16x8 A1;
        A1[0] = f2bf(lo.x); A1[1] = f2bf(lo.y); A1[2] = f2bf(lo.z); A1[3] = f2bf(lo.w);
        A1[4] = f2bf(hi.x); A1[5] = f2bf(hi.y); A1[6] = f2bf(hi.z); A1[7] = f2bf(hi.w);
        wave_lds_sync();                         // EA reads retired before overwrite
        if (gi < 3) ISSUE_EA(gi + 1);            // stage next group's eattr

        // GEMM1 + bias + relu -> T (bf16, A2-readable layout, row stride 72)
        #pragma unroll
        for (int nt = 0; nt < 4; ++nt) {
            f32x4 C = {0.f, 0.f, 0.f, 0.f};
            C = __builtin_amdgcn_mfma_f32_16x16x32_bf16(A1, B1f[nt], C, 0, 0, 0);
            #pragma unroll
            for (int r = 0; r < 4; ++r) {
                const float tv = fmaxf(C[r] + b1v[nt], 0.0f);
                T[(quad * 4 + r) * 72 + nt * 16 + col] = f2bf(tv);
            }
        }
        wave_lds_sync();

        // A2-frags: t[m=col][ks*32 + quad*8 .. +7]
        bf16x8 A2_0 = *(const bf16x8*)&T[col * 72 + 0  + quad * 8];
        bf16x8 A2_1 = *(const bf16x8*)&T[col * 72 + 32 + quad * 8];
        wave_lds_sync();

        // GEMM2 + bias -> EM (fp32 rotated [16][64], conflict-free)
        #pragma unroll
        for (int nt = 0; nt < 4; ++nt) {
            f32x4 C = {0.f, 0.f, 0.f, 0.f};
            C = __builtin_amdgcn_mfma_f32_16x16x32_bf16(A2_0, B2f[0][nt], C, 0, 0, 0);
            C = __builtin_amdgcn_mfma_f32_16x16x32_bf16(A2_1, B2f[1][nt], C, 0, 0, 0);
            #pragma unroll
            for (int r = 0; r < 4; ++r)
                EM[EMIDX(quad * 4 + r, nt * 16 + col)] = C[r] + b2v[nt];
        }
        wave_lds_sync();

        // HG[gi] resident: 2 younger DMA loads (EA[gi+1]) for gi<3, 0 at tail
        if (gi < 3) { WAITVM(2); } else { WAITVM(0); }
        __builtin_amdgcn_sched_barrier(0);

        // phase 2: segmented accumulate from LDS; flush on dst change
        #pragma unroll
        for (int e2 = 0; e2 < 16; ++e2) {
            const int d = __builtin_amdgcn_readlane(dv_all, gi * 16 + e2); // uniform
            const float msg = fmaxf(HG[e2 * 64 + lane] + EM[EMIDX(e2, lane)], 0.0f);
            if (d != cur) {                        // uniform branch
                if (cur >= 0) atomicAdd(&agg[(size_t)cur * HH + lane], acc);
                acc = 0.0f; cur = d;
            }
            acc += msg;
        }
        wave_lds_sync();                           // HG/EM reads retired
        if (gi < 3) ISSUE_HG(gi + 1);              // stage next group's gathers
    }
    if (cur >= 0) atomicAdd(&agg[(size_t)cur * HH + lane], acc);
    #undef ISSUE_EA
    #undef ISSUE_HG
}

// ---------------------------------------------------------------------------
// Node pass v7: MFMA GEMM pair with 3-term bf16 split (proven round 5),
// em re-expressed as rotated stride-64 -> LDS 53248B/block -> 3 blocks/CU
// (12 waves, was 8). Weight LDS layout unchanged (stride-72 shorts).
__global__ __launch_bounds__(256, 3) void node_mfma(
    const float* __restrict__ hin,
    float*       agg,                    // in: agg, out: v (same rows only)
    const float* __restrict__ w1, const float* __restrict__ b1,
    const float* __restrict__ w2, const float* __restrict__ b2,
    const float* __restrict__ epsp,
    float*       __restrict__ stats)     // [0:64] sum, [64:128] sumsq
{
    __shared__ short wt[4][64 * 72];     // W1h, W1l, W2h, W2l : [n][k] bf16
    __shared__ float em[4][16 * 64];     // per-wave t/v handoff (rotated)

    const int tid = threadIdx.x;
    // stage weights (block-shared), hi/lo split, transposed
    for (int idx = tid; idx < HH * HH; idx += 256) {
        const int k = idx >> 6, n = idx & 63;
        {
            const float w = w1[idx];
            const short h = f2bf(w);
            wt[0][n * 72 + k] = h;
            wt[1][n * 72 + k] = f2bf(w - bf2f(h));
        }
        {
            const float w = w2[idx];
            const short h = f2bf(w);
            wt[2][n * 72 + k] = h;
            wt[3][n * 72 + k] = f2bf(w - bf2f(h));
        }
    }
    __syncthreads();

    const int lane = tid & 63;
    const int wv   = tid >> 6;
    const int col  = lane & 15;
    const int quad = lane >> 4;
    float* EM = em[wv];
    const float epsv = 1.0f + epsp[0];
    const int wid = blockIdx.x * 4 + wv;

    float b1v[4], b2v[4];
    #pragma unroll
    for (int nt = 0; nt < 4; ++nt) {
        b1v[nt] = b1[nt * 16 + col];
        b2v[nt] = b2[nt * 16 + col];
    }

    float s1 = 0.0f, s2 = 0.0f;

    #pragma unroll 1
    for (int gi = 0; gi < 4; ++gi) {
        const int grp = wid * 4 + gi;
        if (grp >= NGRP_N) break;                  // uniform (NN%16==0: no partial groups)
        const int n0  = grp * 16;
        const int row = n0 + col;

        // ---- load z = epsv*h + agg, split into A hi/lo frags (K=64) ----
        bf16x8 Ah[2], Al[2];
        #pragma unroll
        for (int ks = 0; ks < 2; ++ks) {
            const float* hp = hin + (size_t)row * HH + ks * 32 + quad * 8;
            const float* gp = agg + (size_t)row * HH + ks * 32 + quad * 8;
            const float4 h0 = *(const float4*)hp;
            const float4 h1 = *(const float4*)(hp + 4);
            const float4 g0 = *(const float4*)gp;
            const float4 g1 = *(const float4*)(gp + 4);
            float z[8];
            z[0] = fmaf(epsv, h0.x, g0.x); z[1] = fmaf(epsv, h0.y, g0.y);
            z[2] = fmaf(epsv, h0.z, g0.z); z[3] = fmaf(epsv, h0.w, g0.w);
            z[4] = fmaf(epsv, h1.x, g1.x); z[5] = fmaf(epsv, h1.y, g1.y);
            z[6] = fmaf(epsv, h1.z, g1.z); z[7] = fmaf(epsv, h1.w, g1.w);
            #pragma unroll
            for (int j = 0; j < 8; ++j) {
                const short h = f2bf(z[j]);
                Ah[ks][j] = h;
                Al[ks][j] = f2bf(z[j] - bf2f(h));
            }
        }

        // ---- GEMM1 (3-term) + bias + relu -> EM (rotated [16][64]) ----
        #pragma unroll
        for (int nt = 0; nt < 4; ++nt) {
            f32x4 C = {0.f, 0.f, 0.f, 0.f};
            #pragma unroll
            for (int ks = 0; ks < 2; ++ks) {
                const int wo = (nt * 16 + col) * 72 + ks * 32 + quad * 8;
                const bf16x8 Bh = *(const bf16x8*)&wt[0][wo];
                const bf16x8 Bl = *(const bf16x8*)&wt[1][wo];
                C = __builtin_amdgcn_mfma_f32_16x16x32_bf16(Ah[ks], Bh, C, 0, 0, 0);
                C = __builtin_amdgcn_mfma_f32_16x16x32_bf16(Al[ks], Bh, C, 0, 0, 0);
                C = __builtin_amdgcn_mfma_f32_16x16x32_bf16(Ah[ks], Bl, C, 0, 0, 0);
            }
            #pragma unroll
            for (int r = 0; r < 4; ++r)
                EM[EMIDX(quad * 4 + r, nt * 16 + col)] = fmaxf(C[r] + b1v[nt], 0.0f);
        }
        wave_lds_sync();

        // ---- read t rows (rotated: start (ks*32+quad*8+col*4)&63, 4-aligned
        //      so each float4 stays within the row) ----
        bf16x8 Th[2], Tl[2];
        #pragma unroll
        for (int ks = 0; ks < 2; ++ks) {
            const int c0 = (ks * 32 + quad * 8 + col * 4) & 63;
            const float* tp = &EM[col * 64 + c0];
            const float4 t0 = *(const float4*)tp;
            const int c1 = (ks * 32 + quad * 8 + 4 + col * 4) & 63;
            const float4 t1 = *(const float4*)&EM[col * 64 + c1];
            float tz[8] = {t0.x, t0.y, t0.z, t0.w, t1.x, t1.y, t1.z, t1.w};
            #pragma unroll
            for (int j = 0; j < 8; ++j) {
                const short h = f2bf(tz[j]);
                Th[ks][j] = h;
                Tl[ks][j] = f2bf(tz[j] - bf2f(h));
            }
        }
        wave_lds_sync();                            // t reads retired before v writes

        // ---- GEMM2 (3-term) + bias + relu -> EM ----
        #pragma unroll
        for (int nt = 0; nt < 4; ++nt) {
            f32x4 C = {0.f, 0.f, 0.f, 0.f};
            #pragma unroll
            for (int ks = 0; ks < 2; ++ks) {
                const int wo = (nt * 16 + col) * 72 + ks * 32 + quad * 8;
                const bf16x8 Bh = *(const bf16x8*)&wt[2][wo];
                const bf16x8 Bl = *(const bf16x8*)&wt[3][wo];
                C = __builtin_amdgcn_mfma_f32_16x16x32_bf16(Th[ks], Bh, C, 0, 0, 0);
                C = __builtin_amdgcn_mfma_f32_16x16x32_bf16(Tl[ks], Bh, C, 0, 0, 0);
                C = __builtin_amdgcn_mfma_f32_16x16x32_bf16(Th[ks], Bl, C, 0, 0, 0);
            }
            #pragma unroll
            for (int r = 0; r < 4; ++r)
                EM[EMIDX(quad * 4 + r, nt * 16 + col)] = fmaxf(C[r] + b2v[nt], 0.0f);
        }
        wave_lds_sync();

        // ---- coalesced store to agg + BN partial sums (lane = feature) ----
        #pragma unroll 4
        for (int e2 = 0; e2 < 16; ++e2) {
            const float val = EM[EMIDX(e2, lane)];
            agg[(size_t)(n0 + e2) * HH + lane] = val;
            s1 += val;
            s2 += val * val;
        }
        wave_lds_sync();                            // v reads retired before next group
    }
    atomicAdd(&stats[lane], s1);
    atomicAdd(&stats[64 + lane], s2);
}

// ---------------------------------------------------------------------------
// BN apply + segmented graph-pool accumulation (batch sorted).
// Folds bn_finalize (mu/rsig computed in-wave from raw stats).
#define CHUNK 32
__global__ void bn_apply(
    const float* __restrict__ v, const float* __restrict__ stats,
    const float* __restrict__ gamma, const float* __restrict__ beta,
    const int* __restrict__ batch,
    float* __restrict__ hout, float* __restrict__ pooled, int layer)
{
    const int lane = threadIdx.x & 63;
    const int wv   = (blockIdx.x * blockDim.x + threadIdx.x) >> 6;
    const int n0   = wv * CHUNK;
    if (n0 >= NN) return;
    const int n1 = min(n0 + CHUNK, NN);
    const float mu  = stats[lane] * (1.0f / NN);
    const float var = stats[64 + lane] * (1.0f / NN) - mu * mu;
    const float rs  = 1.0f / sqrtf(var + 1e-5f);
    const float ga = gamma[lane],       be = beta[lane];
    float acc = 0.0f;
    int cur = batch[n0];
    for (int n = n0; n < n1; ++n) {
        const int b = batch[n];                       // uniform
        const float z = (v[(size_t)n * HH + lane] - mu) * rs * ga + be;
        hout[(size_t)n * HH + lane] = z;
        if (b != cur) {                               // uniform branch
            atomicAdd(&pooled[(size_t)cur * (NL * HH) + layer * HH + lane], acc);
            acc = 0.0f; cur = b;
        }
        acc += z;
    }
    atomicAdd(&pooled[(size_t)cur * (NL * HH) + layer * HH + lane], acc);
}

// ---------------------------------------------------------------------------
__global__ __launch_bounds__(256, 1) void graph_kernel(
    const float* __restrict__ pooled, const float* __restrict__ cnt,
    const float* __restrict__ fc0_w, const float* __restrict__ fc0_b,
    const float* __restrict__ wts, const int* __restrict__ sgb,
    float* __restrict__ s_acc)
{
    __shared__ float w[NL * HH * HH];   // 48KB
    for (int i = threadIdx.x; i < NL * HH * HH; i += blockDim.x) w[i] = fc0_w[i];
    __syncthreads();
    const int lane = threadIdx.x & 63;
    const int g = blockIdx.x * 4 + (threadIdx.x >> 6);
    if (g >= NG) return;
    const float inv = 1.0f / fmaxf(cnt[g], 1.0f);
    float acc = fc0_b[lane];
    #pragma unroll
    for (int c = 0; c < NL; ++c) {
        const float a = pooled[g * (NL * HH) + c * HH + lane] * inv;
        #pragma unroll
        for (int k = 0; k < HH; ++k)
            acc = fmaf(bcastf(a, k), w[(c * HH + k) * HH + lane], acc);
    }
    const float og = fmaxf(acc, 0.0f) * wts[g];
    atomicAdd(&s_acc[sgb[g] * HH + lane], og);
}

__global__ __launch_bounds__(256, 1) void final_kernel(
    const float* __restrict__ s_acc, const float* __restrict__ norm,
    const float* __restrict__ fc1_w, const float* __restrict__ fc1_b,
    const float* __restrict__ fc2_w, const float* __restrict__ fc2_b,
    const float* __restrict__ pw, const float* __restrict__ pb,
    float* __restrict__ out)
{
    const int lane = threadIdx.x & 63;
    const int s = blockIdx.x * 4 + (threadIdx.x >> 6);
    if (s >= NSG) return;
    const float xv = s_acc[s * HH + lane] / fmaxf(norm[s], 1e-12f);
    float u = fc1_b[lane];
    #pragma unroll
    for (int k = 0; k < HH; ++k) u = fmaf(bcastf(xv, k), fc1_w[k * HH + lane], u);
    u = fmaxf(u, 0.0f);
    float v = fc2_b[lane];
    #pragma unroll
    for (int k = 0; k < HH; ++k) v = fmaf(bcastf(u, k), fc2_w[k * HH + lane], v);
    v = fmaxf(v, 0.0f);
    float o = pb[lane & 31];
    #pragma unroll
    for (int k = 0; k < HH; ++k) o = fmaf(bcastf(v, k), pw[k * NOUT + (lane & 31)], o);
    if (lane < NOUT) out[s * NOUT + lane] = o;
}

// ---------------------------------------------------------------------------
extern "C" void kernel_launch(void* const* d_in, const int* in_sizes, int n_in,
                              void* d_out, int out_size, void* d_ws, size_t ws_size,
                              hipStream_t stream)
{
    const float* x        = (const float*)d_in[0];
    const int*   eidx     = (const int*)d_in[1];
    const float* eattr    = (const float*)d_in[2];
    const int*   batch    = (const int*)d_in[3];
    const float* weights  = (const float*)d_in[4];
    const int*   sgb      = (const int*)d_in[5];
    const float* be_w1    = (const float*)d_in[6];
    const float* be_b1    = (const float*)d_in[7];
    const float* be_w2    = (const float*)d_in[8];
    const float* be_b2    = (const float*)d_in[9];
    const float* mlp_w1   = (const float*)d_in[10];
    const float* mlp_b1   = (const float*)d_in[11];
    const float* mlp_w2   = (const float*)d_in[12];
    const float* mlp_b2   = (const float*)d_in[13];
    const float* eps      = (const float*)d_in[14];
    const float* bn_gamma = (const float*)d_in[15];
    const float* bn_beta  = (const float*)d_in[16];
    const float* fc0_w    = (const float*)d_in[17];
    const float* fc0_b    = (const float*)d_in[18];
    const float* fc1_w    = (const float*)d_in[19];
    const float* fc1_b    = (const float*)d_in[20];
    const float* fc2_w    = (const float*)d_in[21];
    const float* fc2_b    = (const float*)d_in[22];
    const float* pred_w   = (const float*)d_in[23];
    const float* pred_b   = (const float*)d_in[24];
    float* out = (float*)d_out;

    float* ws     = (float*)d_ws;
    float* h_buf  = ws;                               // NN*64
    float* agg    = ws + (size_t)NN * HH;             // NN*64 (also holds v)
    float* stats  = ws + (size_t)NN * HH * 2;         // 256 (right after agg!)
    float* pooled = stats + 256;                      // NG*192
    float* cnt    = pooled + (size_t)NG * NL * HH;    // NG
    float* s_acc  = cnt + NG;                         // NSG*64
    float* norm   = s_acc + (size_t)NSG * HH;         // NSG
    int*   ioff   = (int*)(norm + NSG);               // NN   (hist -> offsets -> cursors)
    int*   bsum   = ioff + NN;                        // 512
    int*   perm_s = bsum + 512;                       // NE
    int*   src_s  = perm_s + NE;                      // NE
    int*   dst_s  = src_s + NE;                       // NE

    size_t acc_floats = (size_t)NG * NL * HH + NG + (size_t)NSG * HH + NSG;
    hipMemsetAsync(pooled, 0, acc_floats * sizeof(float), stream);
    hipMemsetAsync(ioff, 0, NN * sizeof(int), stream);

    // ---- counting sort of edges by dst (once per call, reused by 3 layers)
    const int nb = (NN + 255) / 256;                  // 391 blocks
    hist_kernel<<<(NE + 255) / 256, 256, 0, stream>>>(eidx, ioff);
    scan1<<<nb, 256, 0, stream>>>(ioff, bsum);
    scan2<<<1, 512, 0, stream>>>(bsum, nb);
    scan3<<<nb, 256, 0, stream>>>(ioff, bsum);
    scatter_kernel<<<(NE + 255) / 256, 256, 0, stream>>>(eidx, ioff, perm_s, src_s, dst_s);

    prep_kernel<<<(NN + 255) / 256, 256, 0, stream>>>(batch, sgb, weights, cnt, norm);

    const float* hin = x;
    const int eblocks = (NWAVE + 3) / 4;              // 3907
    const int node_blocks = (NGRP_N + 15) / 16;       // 391 (16 groups / block)
    const int bn_waves  = (NN + CHUNK - 1) / CHUNK;
    const int bn_blocks = (bn_waves + 3) / 4;
    for (int l = 0; l < NL; ++l) {
        // one memset covers agg AND stats (adjacent in ws)
        hipMemsetAsync(agg, 0, ((size_t)NN * HH + 256) * sizeof(float), stream);
        edge_mfma<<<eblocks, 256, 0, stream>>>(
            hin, eattr, perm_s, src_s, dst_s,
            be_w1 + l * EF * HH, be_b1 + l * HH,
            be_w2 + l * HH * HH, be_b2 + l * HH, agg);
        node_mfma<<<node_blocks, 256, 0, stream>>>(
            hin, agg,
            mlp_w1 + l * HH * HH, mlp_b1 + l * HH,
            mlp_w2 + l * HH * HH, mlp_b2 + l * HH,
            eps + l, stats);
        bn_apply<<<bn_blocks, 256, 0, stream>>>(
            agg, stats, bn_gamma + l * HH, bn_beta + l * HH,
            batch, h_buf, pooled, l);
        hin = h_buf;
    }

    graph_kernel<<<NG / 4, 256, 0, stream>>>(pooled, cnt, fc0_w, fc0_b,
                                             weights, sgb, s_acc);
    final_kernel<<<NSG / 4, 256, 0, stream>>>(s_acc, norm, fc1_w, fc1_b,
                                              fc2_w, fc2_b, pred_w, pred_b, out);
}

// Round 8
// 848.996 us; speedup vs baseline: 1.0697x; 1.0697x over previous
//
#include <hip/hip_runtime.h>

#define NN 100000      // nodes
#define NE 1000000     // edges
#define NG 1024        // graphs
#define NSG 128        // subgraphs
#define EF 32          // edge feature dim
#define HH 64          // hidden
#define NOUT 32        // output classes
#define NL 3           // layers
#define NWAVE (NE / 64)   // 15625 edge waves, 64 edges (4 groups) each
#define NGRP_N (NN / 16)  // 6250 node groups of 16
#define EBLOCKS ((NWAVE + 3) / 4)   // 3907

typedef __attribute__((ext_vector_type(8))) short bf16x8;
typedef __attribute__((ext_vector_type(4))) float f32x4;

// rotated index for node_mfma's em: stride 64 with per-row column rotation
#define EMIDX(row, c) ((row) * 64 + (((c) + (row) * 4) & 63))

// wave-uniform broadcast of lane l's value (v_readlane -> SGPR)
__device__ __forceinline__ float bcastf(float v, int l) {
    return __int_as_float(__builtin_amdgcn_readlane(__float_as_int(v), l));
}

// fp32 -> bf16 (RNE)
__device__ __forceinline__ short f2bf(float x) {
    unsigned u = __float_as_uint(x);
    u += 0x7FFFu + ((u >> 16) & 1u);
    return (short)(u >> 16);
}

// bf16 -> fp32 (exact)
__device__ __forceinline__ float bf2f(short h) {
    return __uint_as_float(((unsigned)(unsigned short)h) << 16);
}

// wave-internal LDS producer->consumer handoff (no cross-wave sharing)
__device__ __forceinline__ void wave_lds_sync() {
    __builtin_amdgcn_wave_barrier();
    asm volatile("s_waitcnt lgkmcnt(0)" ::: "memory");
    __builtin_amdgcn_wave_barrier();
}

// async global->LDS, 16B per lane; LDS dest = wave-uniform base + lane*16
__device__ __forceinline__ void gld16(const float* g, float* l) {
    __builtin_amdgcn_global_load_lds(
        (const __attribute__((address_space(1))) void*)g,
        (__attribute__((address_space(3))) void*)l, 16, 0, 0);
}

#define WAITVM_(n) asm volatile("s_waitcnt vmcnt(" #n ")" ::: "memory")
#define WAITVM(n) WAITVM_(n)

// ---------------------------------------------------------------------------
// cnt (graph node counts) + norm (subgraph weight sums) in one launch
__global__ void prep_kernel(const int* __restrict__ batch, const int* __restrict__ sgb,
                            const float* __restrict__ w,
                            float* __restrict__ cnt, float* __restrict__ norm) {
    int i = blockIdx.x * blockDim.x + threadIdx.x;
    if (i < NN) atomicAdd(&cnt[batch[i]], 1.0f);
    if (i < NG) atomicAdd(&norm[sgb[i]], w[i]);
}

// --------------------------- edge counting-sort ----------------------------
__global__ void hist_kernel(const int* __restrict__ eidx, int* __restrict__ off) {
    int e = blockIdx.x * 256 + threadIdx.x;
    if (e < NE) atomicAdd(&off[eidx[NE + e]], 1);
}

__global__ void scan1(int* __restrict__ off, int* __restrict__ bsum) {
    __shared__ int s[256];
    const int i = blockIdx.x * 256 + threadIdx.x;
    const int v = (i < NN) ? off[i] : 0;
    s[threadIdx.x] = v; __syncthreads();
    for (int d = 1; d < 256; d <<= 1) {
        const int t = (threadIdx.x >= d) ? s[threadIdx.x - d] : 0;
        __syncthreads(); s[threadIdx.x] += t; __syncthreads();
    }
    if (i < NN) off[i] = s[threadIdx.x] - v;          // exclusive
    if (threadIdx.x == 255) bsum[blockIdx.x] = s[255];
}

__global__ void scan2(int* __restrict__ bsum, int nb) {
    __shared__ int s[512];
    const int v = (threadIdx.x < nb) ? bsum[threadIdx.x] : 0;
    s[threadIdx.x] = v; __syncthreads();
    for (int d = 1; d < 512; d <<= 1) {
        const int t = (threadIdx.x >= d) ? s[threadIdx.x - d] : 0;
        __syncthreads(); s[threadIdx.x] += t; __syncthreads();
    }
    if (threadIdx.x < nb) bsum[threadIdx.x] = s[threadIdx.x] - v;  // exclusive
}

__global__ void scan3(int* __restrict__ off, const int* __restrict__ bsum) {
    const int i = blockIdx.x * 256 + threadIdx.x;
    if (i < NN) off[i] += bsum[blockIdx.x];
}

__global__ void scatter_kernel(const int* __restrict__ eidx, int* __restrict__ off,
                               int* __restrict__ perm_s, int* __restrict__ src_s,
                               int* __restrict__ dst_s) {
    int e = blockIdx.x * 256 + threadIdx.x;
    if (e < NE) {
        const int d = eidx[NE + e];
        const int p = atomicAdd(&off[d], 1);
        perm_s[p] = e;
        src_s[p]  = eidx[e];
        dst_s[p]  = d;
    }
}

// ---------------------------------------------------------------------------
// Edge pass via MFMA over dst-SORTED edges.
// v8: byte-identical v5 pipeline (proven 96us) + bijective XCD-aware block
// swizzle (m204): contiguous chunks of the dst-sorted edge space map to one
// XCD, so hin-row sharing and agg atomic lines stay in ONE L2 (r6/r7 showed
// the kernel is L2-locality-bound, not occupancy-bound).
//   issue order: [fence] EA0,HG0 | EA1 .. HG1 | EA2 .. HG2 | EA3 .. HG3
//   EA waits: 4,4,4,4   HG waits: 2,2,2,0   (N <= #younger DMA loads, safe)
__global__ __launch_bounds__(256, 4) void edge_mfma(
    const float* __restrict__ hin,       // [NN,64]
    const float* __restrict__ eattr,     // [NE,32]
    const int*   __restrict__ perm_s,    // [NE] sorted->orig edge id
    const int*   __restrict__ src_s,     // [NE] src of sorted edge
    const int*   __restrict__ dst_s,     // [NE] dst of sorted edge (nondecreasing)
    const float* __restrict__ w1,        // [32,64]
    const float* __restrict__ b1,        // [64]
    const float* __restrict__ w2,        // [64,64]
    const float* __restrict__ b2,        // [64]
    float*       __restrict__ agg)       // [NN,64]
{
    __shared__ float ldsall[4][2624];    // per-wave: EM/T | HG | EA
    const int lane = threadIdx.x & 63;
    const int wv   = threadIdx.x >> 6;
    const int col  = lane & 15;          // MFMA: B col / C col / A row
    const int quad = lane >> 4;
    float* EM = &ldsall[wv][0];          // fp32 [16][68] (GEMM2 out)
    short* T  = (short*)EM;              // bf16 [16][72] union (GEMM1 out)
    float* HG = &ldsall[wv][1088];       // fp32 [16][64] gathered hin rows
    float* EA = &ldsall[wv][2112];       // fp32 [16][32] eattr rows (chunk-swizzled)

    // bijective XCD swizzle: xcd = bid%8 owns a CONTIGUOUS chunk of blocks
    const int bid = blockIdx.x;
    const int xcd = bid & 7, loc = bid >> 3;
    const int q = EBLOCKS >> 3, r = EBLOCKS & 7;
    const int sbid = (xcd < r ? xcd * (q + 1) : r * (q + 1) + (xcd - r) * q) + loc;

    const int wid = __builtin_amdgcn_readfirstlane(
        (sbid * 256 + (int)threadIdx.x) >> 6);
    if (wid >= NWAVE) return;
    const int ebase = wid * 64;

    // --- weight fragments, built once per wave ---
    bf16x8 B1f[4];
    #pragma unroll
    for (int nt = 0; nt < 4; ++nt)
        #pragma unroll
        for (int j = 0; j < 8; ++j)
            B1f[nt][j] = f2bf(w1[(quad * 8 + j) * HH + nt * 16 + col]);
    bf16x8 B2f[2][4];
    #pragma unroll
    for (int ks = 0; ks < 2; ++ks)
        #pragma unroll
        for (int nt = 0; nt < 4; ++nt)
            #pragma unroll
            for (int j = 0; j < 8; ++j)
                B2f[ks][nt][j] = f2bf(w2[(ks * 32 + quad * 8 + j) * HH + nt * 16 + col]);
    float b1v[4], b2v[4];
    #pragma unroll
    for (int nt = 0; nt < 4; ++nt) {
        b1v[nt] = b1[nt * 16 + col];
        b2v[nt] = b2[nt * 16 + col];
    }

    // --- whole-wave edge indices (one load each, resident all 4 groups) ---
    const int sv_all = src_s[ebase + lane];
    const int dv_all = dst_s[ebase + lane];
    const int pe_all = perm_s[ebase + lane];

    // EA DMA source swizzle: slot s of row r receives global 16B-chunk s^(r&7)
    const int ea_srcchunk = (lane & 7) ^ ((lane >> 3) & 7);
    const int ea_subrow   = lane >> 3;        // row within 8-row DMA block
    const int hg_subrow   = lane >> 4;        // row within 4-row DMA block
    const int hg_off      = (lane & 15) * 4;  // float offset within hin row

    // 2 DMAs staging group g's 16 eattr rows (128B each) into EA
    #define ISSUE_EA(g)                                                        \
        {                                                                      \
            _Pragma("unroll")                                                  \
            for (int b = 0; b < 2; ++b) {                                      \
                const int srow = (g) * 16 + b * 8 + ea_subrow;                 \
                const int pe   = __shfl(pe_all, srow, 64);                     \
                gld16(eattr + (size_t)pe * EF + ea_srcchunk * 4,               \
                      EA + b * 256);                                           \
            }                                                                  \
        }
    // 4 DMAs staging group g's 16 hin gather rows (256B each) into HG
    #define ISSUE_HG(g)                                                        \
        {                                                                      \
            _Pragma("unroll")                                                  \
            for (int b = 0; b < 4; ++b) {                                      \
                const int srow = (g) * 16 + b * 4 + hg_subrow;                 \
                const int s    = __shfl(sv_all, srow, 64);                     \
                gld16(hin + (size_t)s * HH + hg_off, HG + b * 256);            \
            }                                                                  \
        }

    // fence: no compiler-scheduled vmem may sit inside the counted FIFO
    WAITVM(0);
    __builtin_amdgcn_sched_barrier(0);

    // prologue: EA0(2), HG0(4)
    ISSUE_EA(0);
    ISSUE_HG(0);

    int   cur = -1;       // current dst segment (wave-uniform)
    float acc = 0.0f;     // per-lane feature accumulator

    #pragma unroll
    for (int gi = 0; gi < 4; ++gi) {
        // EA[gi] resident: 4 younger DMA loads (HG[gi]) in FIFO
        WAITVM(4);
        __builtin_amdgcn_sched_barrier(0);

        // A1-frag from EA (chunk-swizzled): lane reads row=col, chunks 2q,2q+1
        const int sbase = (2 * quad) ^ (col & 6);
        const float4 fa = *(const float4*)&EA[col * 32 + sbase * 4];
        const float4 fb = *(const float4*)&EA[col * 32 + sbase * 4 + 4];
        const bool odd = (col & 1);
        const float4 lo = odd ? fb : fa;
        const float4 hi = odd ? fa : fb;
        bf16x8 A1;
        A1[0] = f2bf(lo.x); A1[1] = f2bf(lo.y); A1[2] = f2bf(lo.z); A1[3] = f2bf(lo.w);
        A1[4] = f2bf(hi.x); A1[5] = f2bf(hi.y); A1[6] = f2bf(hi.z); A1[7] = f2bf(hi.w);
        wave_lds_sync();                         // EA reads retired before overwrite
        if (gi < 3) ISSUE_EA(gi + 1);            // stage next group's eattr

        // GEMM1 + bias + relu -> T (bf16, A2-readable layout, row stride 72)
        #pragma unroll
        for (int nt = 0; nt < 4; ++nt) {
            f32x4 C = {0.f, 0.f, 0.f, 0.f};
            C = __builtin_amdgcn_mfma_f32_16x16x32_bf16(A1, B1f[nt], C, 0, 0, 0);
            #pragma unroll
            for (int r = 0; r < 4; ++r) {
                const float tv = fmaxf(C[r] + b1v[nt], 0.0f);
                T[(quad * 4 + r) * 72 + nt * 16 + col] = f2bf(tv);
            }
        }
        wave_lds_sync();

        // A2-frags: t[m=col][ks*32 + quad*8 .. +7]
        bf16x8 A2_0 = *(const bf16x8*)&T[col * 72 + 0  + quad * 8];
        bf16x8 A2_1 = *(const bf16x8*)&T[col * 72 + 32 + quad * 8];
        wave_lds_sync();

        // GEMM2 + bias -> EM (fp32 [16][68], padded stride)
        #pragma unroll
        for (int nt = 0; nt < 4; ++nt) {
            f32x4 C = {0.f, 0.f, 0.f, 0.f};
            C = __builtin_amdgcn_mfma_f32_16x16x32_bf16(A2_0, B2f[0][nt], C, 0, 0, 0);
            C = __builtin_amdgcn_mfma_f32_16x16x32_bf16(A2_1, B2f[1][nt], C, 0, 0, 0);
            #pragma unroll
            for (int r = 0; r < 4; ++r)
                EM[(quad * 4 + r) * 68 + nt * 16 + col] = C[r] + b2v[nt];
        }
        wave_lds_sync();

        // HG[gi] resident: 2 younger DMA loads (EA[gi+1]) for gi<3, 0 at tail
        if (gi < 3) { WAITVM(2); } else { WAITVM(0); }
        __builtin_amdgcn_sched_barrier(0);

        // phase 2: segmented accumulate from LDS; flush on dst change
        #pragma unroll
        for (int e2 = 0; e2 < 16; ++e2) {
            const int d = __builtin_amdgcn_readlane(dv_all, gi * 16 + e2); // uniform
            const float msg = fmaxf(HG[e2 * 64 + lane] + EM[e2 * 68 + lane], 0.0f);
            if (d != cur) {                        // uniform branch
                if (cur >= 0) atomicAdd(&agg[(size_t)cur * HH + lane], acc);
                acc = 0.0f; cur = d;
            }
            acc += msg;
        }
        wave_lds_sync();                           // HG/EM reads retired
        if (gi < 3) ISSUE_HG(gi + 1);              // stage next group's gathers
    }
    if (cur >= 0) atomicAdd(&agg[(size_t)cur * HH + lane], acc);
    #undef ISSUE_EA
    #undef ISSUE_HG
}

// ---------------------------------------------------------------------------
// Node pass v7: MFMA GEMM pair with 3-term bf16 split (proven), rotated em
// (stride-64 + per-row rotation) -> 53248B/block -> 3 blocks/CU.
__global__ __launch_bounds__(256, 3) void node_mfma(
    const float* __restrict__ hin,
    float*       agg,                    // in: agg, out: v (same rows only)
    const float* __restrict__ w1, const float* __restrict__ b1,
    const float* __restrict__ w2, const float* __restrict__ b2,
    const float* __restrict__ epsp,
    float*       __restrict__ stats)     // [0:64] sum, [64:128] sumsq
{
    __shared__ short wt[4][64 * 72];     // W1h, W1l, W2h, W2l : [n][k] bf16
    __shared__ float em[4][16 * 64];     // per-wave t/v handoff (rotated)

    const int tid = threadIdx.x;
    // stage weights (block-shared), hi/lo split, transposed
    for (int idx = tid; idx < HH * HH; idx += 256) {
        const int k = idx >> 6, n = idx & 63;
        {
            const float w = w1[idx];
            const short h = f2bf(w);
            wt[0][n * 72 + k] = h;
            wt[1][n * 72 + k] = f2bf(w - bf2f(h));
        }
        {
            const float w = w2[idx];
            const short h = f2bf(w);
            wt[2][n * 72 + k] = h;
            wt[3][n * 72 + k] = f2bf(w - bf2f(h));
        }
    }
    __syncthreads();

    const int lane = tid & 63;
    const int wv   = tid >> 6;
    const int col  = lane & 15;
    const int quad = lane >> 4;
    float* EM = em[wv];
    const float epsv = 1.0f + epsp[0];
    const int wid = blockIdx.x * 4 + wv;

    float b1v[4], b2v[4];
    #pragma unroll
    for (int nt = 0; nt < 4; ++nt) {
        b1v[nt] = b1[nt * 16 + col];
        b2v[nt] = b2[nt * 16 + col];
    }

    float s1 = 0.0f, s2 = 0.0f;

    #pragma unroll 1
    for (int gi = 0; gi < 4; ++gi) {
        const int grp = wid * 4 + gi;
        if (grp >= NGRP_N) break;                  // uniform (NN%16==0: no partial groups)
        const int n0  = grp * 16;
        const int row = n0 + col;

        // ---- load z = epsv*h + agg, split into A hi/lo frags (K=64) ----
        bf16x8 Ah[2], Al[2];
        #pragma unroll
        for (int ks = 0; ks < 2; ++ks) {
            const float* hp = hin + (size_t)row * HH + ks * 32 + quad * 8;
            const float* gp = agg + (size_t)row * HH + ks * 32 + quad * 8;
            const float4 h0 = *(const float4*)hp;
            const float4 h1 = *(const float4*)(hp + 4);
            const float4 g0 = *(const float4*)gp;
            const float4 g1 = *(const float4*)(gp + 4);
            float z[8];
            z[0] = fmaf(epsv, h0.x, g0.x); z[1] = fmaf(epsv, h0.y, g0.y);
            z[2] = fmaf(epsv, h0.z, g0.z); z[3] = fmaf(epsv, h0.w, g0.w);
            z[4] = fmaf(epsv, h1.x, g1.x); z[5] = fmaf(epsv, h1.y, g1.y);
            z[6] = fmaf(epsv, h1.z, g1.z); z[7] = fmaf(epsv, h1.w, g1.w);
            #pragma unroll
            for (int j = 0; j < 8; ++j) {
                const short h = f2bf(z[j]);
                Ah[ks][j] = h;
                Al[ks][j] = f2bf(z[j] - bf2f(h));
            }
        }

        // ---- GEMM1 (3-term) + bias + relu -> EM (rotated [16][64]) ----
        #pragma unroll
        for (int nt = 0; nt < 4; ++nt) {
            f32x4 C = {0.f, 0.f, 0.f, 0.f};
            #pragma unroll
            for (int ks = 0; ks < 2; ++ks) {
                const int wo = (nt * 16 + col) * 72 + ks * 32 + quad * 8;
                const bf16x8 Bh = *(const bf16x8*)&wt[0][wo];
                const bf16x8 Bl = *(const bf16x8*)&wt[1][wo];
                C = __builtin_amdgcn_mfma_f32_16x16x32_bf16(Ah[ks], Bh, C, 0, 0, 0);
                C = __builtin_amdgcn_mfma_f32_16x16x32_bf16(Al[ks], Bh, C, 0, 0, 0);
                C = __builtin_amdgcn_mfma_f32_16x16x32_bf16(Ah[ks], Bl, C, 0, 0, 0);
            }
            #pragma unroll
            for (int r = 0; r < 4; ++r)
                EM[EMIDX(quad * 4 + r, nt * 16 + col)] = fmaxf(C[r] + b1v[nt], 0.0f);
        }
        wave_lds_sync();

        // ---- read t rows (rotated; float4 4-aligned stays in-row) ----
        bf16x8 Th[2], Tl[2];
        #pragma unroll
        for (int ks = 0; ks < 2; ++ks) {
            const int c0 = (ks * 32 + quad * 8 + col * 4) & 63;
            const float4 t0 = *(const float4*)&EM[col * 64 + c0];
            const int c1 = (ks * 32 + quad * 8 + 4 + col * 4) & 63;
            const float4 t1 = *(const float4*)&EM[col * 64 + c1];
            float tz[8] = {t0.x, t0.y, t0.z, t0.w, t1.x, t1.y, t1.z, t1.w};
            #pragma unroll
            for (int j = 0; j < 8; ++j) {
                const short h = f2bf(tz[j]);
                Th[ks][j] = h;
                Tl[ks][j] = f2bf(tz[j] - bf2f(h));
            }
        }
        wave_lds_sync();                            // t reads retired before v writes

        // ---- GEMM2 (3-term) + bias + relu -> EM ----
        #pragma unroll
        for (int nt = 0; nt < 4; ++nt) {
            f32x4 C = {0.f, 0.f, 0.f, 0.f};
            #pragma unroll
            for (int ks = 0; ks < 2; ++ks) {
                const int wo = (nt * 16 + col) * 72 + ks * 32 + quad * 8;
                const bf16x8 Bh = *(const bf16x8*)&wt[2][wo];
                const bf16x8 Bl = *(const bf16x8*)&wt[3][wo];
                C = __builtin_amdgcn_mfma_f32_16x16x32_bf16(Th[ks], Bh, C, 0, 0, 0);
                C = __builtin_amdgcn_mfma_f32_16x16x32_bf16(Tl[ks], Bh, C, 0, 0, 0);
                C = __builtin_amdgcn_mfma_f32_16x16x32_bf16(Th[ks], Bl, C, 0, 0, 0);
            }
            #pragma unroll
            for (int r = 0; r < 4; ++r)
                EM[EMIDX(quad * 4 + r, nt * 16 + col)] = fmaxf(C[r] + b2v[nt], 0.0f);
        }
        wave_lds_sync();

        // ---- coalesced store to agg + BN partial sums (lane = feature) ----
        #pragma unroll 4
        for (int e2 = 0; e2 < 16; ++e2) {
            const float val = EM[EMIDX(e2, lane)];
            agg[(size_t)(n0 + e2) * HH + lane] = val;
            s1 += val;
            s2 += val * val;
        }
        wave_lds_sync();                            // v reads retired before next group
    }
    atomicAdd(&stats[lane], s1);
    atomicAdd(&stats[64 + lane], s2);
}

// ---------------------------------------------------------------------------
// BN apply + segmented graph-pool accumulation (batch sorted).
// v8: also ZEROES the agg rows it owns (replaces the per-layer memset) when
// clr != 0; stats is the per-layer slice (zeroed once upfront).
#define CHUNK 32
__global__ void bn_apply(
    const float* __restrict__ v, float* __restrict__ aggz,
    const float* __restrict__ stats,
    const float* __restrict__ gamma, const float* __restrict__ beta,
    const int* __restrict__ batch,
    float* __restrict__ hout, float* __restrict__ pooled, int layer, int clr)
{
    const int lane = threadIdx.x & 63;
    const int wv   = (blockIdx.x * blockDim.x + threadIdx.x) >> 6;
    const int n0   = wv * CHUNK;
    if (n0 >= NN) return;
    const int n1 = min(n0 + CHUNK, NN);
    const float mu  = stats[lane] * (1.0f / NN);
    const float var = stats[64 + lane] * (1.0f / NN) - mu * mu;
    const float rs  = 1.0f / sqrtf(var + 1e-5f);
    const float ga = gamma[lane],       be = beta[lane];
    float acc = 0.0f;
    int cur = batch[n0];
    for (int n = n0; n < n1; ++n) {
        const int b = batch[n];                       // uniform
        const float z = (v[(size_t)n * HH + lane] - mu) * rs * ga + be;
        hout[(size_t)n * HH + lane] = z;
        if (clr) aggz[(size_t)n * HH + lane] = 0.0f;  // pre-zero for next layer
        if (b != cur) {                               // uniform branch
            atomicAdd(&pooled[(size_t)cur * (NL * HH) + layer * HH + lane], acc);
            acc = 0.0f; cur = b;
        }
        acc += z;
    }
    atomicAdd(&pooled[(size_t)cur * (NL * HH) + layer * HH + lane], acc);
}

// ---------------------------------------------------------------------------
__global__ __launch_bounds__(256, 1) void graph_kernel(
    const float* __restrict__ pooled, const float* __restrict__ cnt,
    const float* __restrict__ fc0_w, const float* __restrict__ fc0_b,
    const float* __restrict__ wts, const int* __restrict__ sgb,
    float* __restrict__ s_acc)
{
    __shared__ float w[NL * HH * HH];   // 48KB
    for (int i = threadIdx.x; i < NL * HH * HH; i += blockDim.x) w[i] = fc0_w[i];
    __syncthreads();
    const int lane = threadIdx.x & 63;
    const int g = blockIdx.x * 4 + (threadIdx.x >> 6);
    if (g >= NG) return;
    const float inv = 1.0f / fmaxf(cnt[g], 1.0f);
    float acc = fc0_b[lane];
    #pragma unroll
    for (int c = 0; c < NL; ++c) {
        const float a = pooled[g * (NL * HH) + c * HH + lane] * inv;
        #pragma unroll
        for (int k = 0; k < HH; ++k)
            acc = fmaf(bcastf(a, k), w[(c * HH + k) * HH + lane], acc);
    }
    const float og = fmaxf(acc, 0.0f) * wts[g];
    atomicAdd(&s_acc[sgb[g] * HH + lane], og);
}

__global__ __launch_bounds__(256, 1) void final_kernel(
    const float* __restrict__ s_acc, const float* __restrict__ norm,
    const float* __restrict__ fc1_w, const float* __restrict__ fc1_b,
    const float* __restrict__ fc2_w, const float* __restrict__ fc2_b,
    const float* __restrict__ pw, const float* __restrict__ pb,
    float* __restrict__ out)
{
    const int lane = threadIdx.x & 63;
    const int s = blockIdx.x * 4 + (threadIdx.x >> 6);
    if (s >= NSG) return;
    const float xv = s_acc[s * HH + lane] / fmaxf(norm[s], 1e-12f);
    float u = fc1_b[lane];
    #pragma unroll
    for (int k = 0; k < HH; ++k) u = fmaf(bcastf(xv, k), fc1_w[k * HH + lane], u);
    u = fmaxf(u, 0.0f);
    float v = fc2_b[lane];
    #pragma unroll
    for (int k = 0; k < HH; ++k) v = fmaf(bcastf(u, k), fc2_w[k * HH + lane], v);
    v = fmaxf(v, 0.0f);
    float o = pb[lane & 31];
    #pragma unroll
    for (int k = 0; k < HH; ++k) o = fmaf(bcastf(v, k), pw[k * NOUT + (lane & 31)], o);
    if (lane < NOUT) out[s * NOUT + lane] = o;
}

// ---------------------------------------------------------------------------
extern "C" void kernel_launch(void* const* d_in, const int* in_sizes, int n_in,
                              void* d_out, int out_size, void* d_ws, size_t ws_size,
                              hipStream_t stream)
{
    const float* x        = (const float*)d_in[0];
    const int*   eidx     = (const int*)d_in[1];
    const float* eattr    = (const float*)d_in[2];
    const int*   batch    = (const int*)d_in[3];
    const float* weights  = (const float*)d_in[4];
    const int*   sgb      = (const int*)d_in[5];
    const float* be_w1    = (const float*)d_in[6];
    const float* be_b1    = (const float*)d_in[7];
    const float* be_w2    = (const float*)d_in[8];
    const float* be_b2    = (const float*)d_in[9];
    const float* mlp_w1   = (const float*)d_in[10];
    const float* mlp_b1   = (const float*)d_in[11];
    const float* mlp_w2   = (const float*)d_in[12];
    const float* mlp_b2   = (const float*)d_in[13];
    const float* eps      = (const float*)d_in[14];
    const float* bn_gamma = (const float*)d_in[15];
    const float* bn_beta  = (const float*)d_in[16];
    const float* fc0_w    = (const float*)d_in[17];
    const float* fc0_b    = (const float*)d_in[18];
    const float* fc1_w    = (const float*)d_in[19];
    const float* fc1_b    = (const float*)d_in[20];
    const float* fc2_w    = (const float*)d_in[21];
    const float* fc2_b    = (const float*)d_in[22];
    const float* pred_w   = (const float*)d_in[23];
    const float* pred_b   = (const float*)d_in[24];
    float* out = (float*)d_out;

    float* ws     = (float*)d_ws;
    float* h_buf  = ws;                               // NN*64
    float* agg    = ws + (size_t)NN * HH;             // NN*64 (also holds v)
    float* pooled = ws + (size_t)NN * HH * 2;         // NG*192   (zeroed block v)
    float* cnt    = pooled + (size_t)NG * NL * HH;    // NG
    float* stats  = cnt + NG;                         // NL*128 per-layer stats
    float* s_acc  = stats + NL * 128;                 // NSG*64
    float* norm   = s_acc + (size_t)NSG * HH;         // NSG      (zeroed block ^)
    int*   ioff   = (int*)(norm + NSG);               // NN   (hist -> offsets -> cursors)
    int*   bsum   = ioff + NN;                        // 512
    int*   perm_s = bsum + 512;                       // NE
    int*   src_s  = perm_s + NE;                      // NE
    int*   dst_s  = src_s + NE;                       // NE

    size_t acc_floats = (size_t)NG * NL * HH + NG + NL * 128 + (size_t)NSG * HH + NSG;
    hipMemsetAsync(pooled, 0, acc_floats * sizeof(float), stream);
    hipMemsetAsync(agg, 0, (size_t)NN * HH * sizeof(float), stream);   // layer-0 agg
    hipMemsetAsync(ioff, 0, NN * sizeof(int), stream);

    // ---- counting sort of edges by dst (once per call, reused by 3 layers)
    const int nb = (NN + 255) / 256;                  // 391 blocks
    hist_kernel<<<(NE + 255) / 256, 256, 0, stream>>>(eidx, ioff);
    scan1<<<nb, 256, 0, stream>>>(ioff, bsum);
    scan2<<<1, 512, 0, stream>>>(bsum, nb);
    scan3<<<nb, 256, 0, stream>>>(ioff, bsum);
    scatter_kernel<<<(NE + 255) / 256, 256, 0, stream>>>(eidx, ioff, perm_s, src_s, dst_s);

    prep_kernel<<<(NN + 255) / 256, 256, 0, stream>>>(batch, sgb, weights, cnt, norm);

    const float* hin = x;
    const int node_blocks = (NGRP_N + 15) / 16;       // 391 (16 groups / block)
    const int bn_waves  = (NN + CHUNK - 1) / CHUNK;
    const int bn_blocks = (bn_waves + 3) / 4;
    for (int l = 0; l < NL; ++l) {
        edge_mfma<<<EBLOCKS, 256, 0, stream>>>(
            hin, eattr, perm_s, src_s, dst_s,
            be_w1 + l * EF * HH, be_b1 + l * HH,
            be_w2 + l * HH * HH, be_b2 + l * HH, agg);
        node_mfma<<<node_blocks, 256, 0, stream>>>(
            hin, agg,
            mlp_w1 + l * HH * HH, mlp_b1 + l * HH,
            mlp_w2 + l * HH * HH, mlp_b2 + l * HH,
            eps + l, stats + l * 128);
        bn_apply<<<bn_blocks, 256, 0, stream>>>(
            agg, agg, stats + l * 128, bn_gamma + l * HH, bn_beta + l * HH,
            batch, h_buf, pooled, l, (l < NL - 1) ? 1 : 0);
        hin = h_buf;
    }

    graph_kernel<<<NG / 4, 256, 0, stream>>>(pooled, cnt, fc0_w, fc0_b,
                                             weights, sgb, s_acc);
    final_kernel<<<NSG / 4, 256, 0, stream>>>(s_acc, norm, fc1_w, fc1_b,
                                              fc2_w, fc2_b, pred_w, pred_b, out);
}